// Round 1
// baseline (253.830 us; speedup 1.0000x reference)
//
#include <hip/hip_runtime.h>

// KNRM forward, MI355X (gfx950).
// One block per batch element; loop over the two (q,d) passes inside the block.
// Matching matrix via 3-term bf16-split MFMA (qh*dh + qh*dl + ql*dh) = fp32-accurate
// to ~1.6e-5 (required by the sigma=0.001 exact-match kernel).
// 21 RBF kernels applied in log2 space: exp(-50(m-mu)^2) = 2^(A m^2) * 2^(B_i m) * 2^(C_i),
// with 2^(C_i) applied once per (q,i) at the reduction (3 VALU ops per element per kernel).

typedef __attribute__((ext_vector_type(8))) short bf16x8;   // 8 bf16 = 4 VGPRs (guide-verified frag type)
typedef __attribute__((ext_vector_type(4))) float f32x4;

__device__ __forceinline__ unsigned short f2bf(float f) {   // RNE float->bf16
    unsigned u = __float_as_uint(f);
    u += 0x7fffu + ((u >> 16) & 1u);
    return (unsigned short)(u >> 16);
}
__device__ __forceinline__ float bf2f(unsigned short h) {
    return __uint_as_float(((unsigned)h) << 16);
}

// Gather 64 embedding rows, L2-normalize, split to bf16 hi/lo, store swizzled.
// Layout: row-major [row][128] bf16 (256B rows = 16 x 16B chunks); element k of row r
// lives in chunk ((k>>3) ^ (r&15)) at sub-offset (k&7). Conflict-free for staging
// writes (permutation across 16 chunks) and for MFMA fragment b128 reads (uniform
// 8 accesses per bank-group).
__device__ __forceinline__ void stage_rows(const float* __restrict__ emb,
                                           const int* __restrict__ ids,
                                           unsigned short* __restrict__ hi,
                                           unsigned short* __restrict__ lo,
                                           int tid)
{
    const int lg = tid >> 5;   // row group 0..7
    const int ln = tid & 31;   // lane within row (32 lanes x float4 = 512B row)
    #pragma unroll
    for (int r0 = 0; r0 < 64; r0 += 8) {
        const int row = r0 + lg;
        const int id  = ids[row];
        const float4 v = *reinterpret_cast<const float4*>(emb + (size_t)id * 128 + ln * 4);
        float ss = v.x*v.x + v.y*v.y + v.z*v.z + v.w*v.w;
        #pragma unroll
        for (int m = 16; m >= 1; m >>= 1) ss += __shfl_xor(ss, m);   // reduce over the 32-lane row group
        const float rn = 1.0f / (sqrtf(ss) + 1e-13f);                // matches reference eps
        const float f0 = v.x*rn, f1 = v.y*rn, f2 = v.z*rn, f3 = v.w*rn;
        const unsigned short h0 = f2bf(f0), h1 = f2bf(f1), h2 = f2bf(f2), h3 = f2bf(f3);
        const unsigned short g0 = f2bf(f0 - bf2f(h0)), g1 = f2bf(f1 - bf2f(h1));
        const unsigned short g2 = f2bf(f2 - bf2f(h2)), g3 = f2bf(f3 - bf2f(h3));
        // lane covers k = 4*ln..4*ln+3 -> chunk = ln>>1, half = ln&1
        const int off = row*128 + (((ln >> 1) ^ (row & 15)) << 3) + ((ln & 1) << 2);
        *reinterpret_cast<uint2*>(hi + off) =
            make_uint2((unsigned)h0 | ((unsigned)h1 << 16), (unsigned)h2 | ((unsigned)h3 << 16));
        *reinterpret_cast<uint2*>(lo + off) =
            make_uint2((unsigned)g0 | ((unsigned)g1 << 16), (unsigned)g2 | ((unsigned)g3 << 16));
    }
}

// Apply the 21 kernels to one matching-matrix value, accumulating raw 2^(A m^2 + B_i m)
// terms (the per-kernel 2^(C_i) scale is applied once at the reduction).
__device__ __forceinline__ void apply_el(float m, float (&sp)[21]) {
    const float a = m * m * (-72.13475204444817f);   // -50*log2(e) * m^2
    #pragma unroll
    for (int i = 0; i < 20; i++) {
        const double mud = -0.95 + 0.1 * (double)i;                  // reference MUS[0..19]
        const float bc = (float)(144.26950408889634 * mud);          // 100*log2(e)*mu
        sp[i] += __builtin_amdgcn_exp2f(fmaf(bc, m, a));             // max arg +65.1, safe
    }
    const float t = m - 1.0f;                                        // exact-match kernel (sigma=1e-3)
    sp[20] += __builtin_amdgcn_exp2f(t * t * (-721347.5204444817f)); // -5e5*log2(e)
}

__global__ __launch_bounds__(256, 2)
void knrm_kernel(const int* __restrict__ q1, const int* __restrict__ d1,
                 const int* __restrict__ q2, const int* __restrict__ d2,
                 const float* __restrict__ emb,
                 const float* __restrict__ W1, const float* __restrict__ b1,
                 const float* __restrict__ W2, const float* __restrict__ b2,
                 const float* __restrict__ W3, const float* __restrict__ b3,
                 float* __restrict__ out)
{
    __shared__ unsigned short qh[64*128], ql[64*128];   // 16 KB each
    __shared__ unsigned short dh[64*128], dl[64*128];   // d processed in 4 chunks of 64 rows
    __shared__ float S[64][21];                         // per-q kernel sums
    __shared__ float KMs[2][21];
    __shared__ float x1s[2][10], x2s[2][5];

    const int tid = threadIdx.x;
    const int bb  = blockIdx.x;
    const int w   = tid >> 6;     // wave 0..3 -> owns q rows 16w..16w+15
    const int l   = tid & 63;
    const int lr  = l & 15;       // MFMA: row-in-tile for A, col (q) for B/C
    const int lh  = l >> 4;       // k-group

    for (int p = 0; p < 2; p++) {
        const int* qids = (p == 0 ? q1 : q2) + bb * 64;
        const int* dids = (p == 0 ? d1 : d2) + bb * 256;

        stage_rows(emb, qids, qh, ql, tid);   // made visible by the chunk-0 barriers below

        float sp[21];
        #pragma unroll
        for (int i = 0; i < 21; i++) sp[i] = 0.0f;

        for (int c = 0; c < 4; c++) {
            __syncthreads();                           // previous chunk's reads (and prev-pass MFMAs) done
            stage_rows(emb, dids + c * 64, dh, dl, tid);
            __syncthreads();                           // staged data visible

            // B (q-side) fragments: my k-mapping = lane-hi picks 8-wide k slice (layout-agnostic in K)
            bf16x8 Bh[4], Bl[4];
            const int qrow = w * 16 + lr;
            #pragma unroll
            for (int ks = 0; ks < 4; ks++) {
                const int off = qrow*128 + (((ks*4 + lh) ^ (qrow & 15)) << 3);
                Bh[ks] = *reinterpret_cast<const bf16x8*>(qh + off);
                Bl[ks] = *reinterpret_cast<const bf16x8*>(ql + off);
            }
            #pragma unroll
            for (int dt = 0; dt < 4; dt += 2) {        // 4 d-tiles per chunk, 2 interleaved chains
                f32x4 C0 = {0.f,0.f,0.f,0.f}, C1 = {0.f,0.f,0.f,0.f};
                #pragma unroll
                for (int ks = 0; ks < 4; ks++) {
                    const int r0 = dt*16 + lr;
                    const int r1 = (dt+1)*16 + lr;
                    const int o0 = r0*128 + (((ks*4 + lh) ^ (r0 & 15)) << 3);
                    const int o1 = r1*128 + (((ks*4 + lh) ^ (r1 & 15)) << 3);
                    const bf16x8 A0h = *reinterpret_cast<const bf16x8*>(dh + o0);
                    const bf16x8 A0l = *reinterpret_cast<const bf16x8*>(dl + o0);
                    const bf16x8 A1h = *reinterpret_cast<const bf16x8*>(dh + o1);
                    const bf16x8 A1l = *reinterpret_cast<const bf16x8*>(dl + o1);
                    C0 = __builtin_amdgcn_mfma_f32_16x16x32_bf16(A0h, Bh[ks], C0, 0, 0, 0);
                    C1 = __builtin_amdgcn_mfma_f32_16x16x32_bf16(A1h, Bh[ks], C1, 0, 0, 0);
                    C0 = __builtin_amdgcn_mfma_f32_16x16x32_bf16(A0h, Bl[ks], C0, 0, 0, 0);
                    C1 = __builtin_amdgcn_mfma_f32_16x16x32_bf16(A1h, Bl[ks], C1, 0, 0, 0);
                    C0 = __builtin_amdgcn_mfma_f32_16x16x32_bf16(A0l, Bh[ks], C0, 0, 0, 0);
                    C1 = __builtin_amdgcn_mfma_f32_16x16x32_bf16(A1l, Bh[ks], C1, 0, 0, 0);
                }
                // C layout: col = lane&15 (one q per lane), rows = 4 d values -> per-lane sp[21]
                #pragma unroll
                for (int r = 0; r < 4; r++) { apply_el(C0[r], sp); apply_el(C1[r], sp); }
            }
        }

        // reduce sp over the 4 lanes sharing a q column, apply 2^(C_i), store S[q][i]
        #pragma unroll
        for (int i = 0; i < 21; i++) {
            float v = sp[i];
            v += __shfl_xor(v, 16);
            v += __shfl_xor(v, 32);
            sp[i] = v;
        }
        if (l < 16) {
            #pragma unroll
            for (int i = 0; i < 21; i++) {
                float dc = 1.0f;
                if (i < 20) {
                    const double mud = -0.95 + 0.1 * (double)i;
                    dc = __builtin_amdgcn_exp2f((float)(-72.13475204444817 * mud * mud));
                }
                S[w*16 + l][i] = sp[i] * dc;
            }
        }
        __syncthreads();   // S visible; also orders all MFMA reads before next-pass staging

        if (tid < 64) {    // wave 0: KM_i = sum_q log1p(S[q][i])
            #pragma unroll
            for (int i = 0; i < 21; i++) {
                float v = log1pf(S[tid][i]);
                #pragma unroll
                for (int m = 1; m <= 32; m <<= 1) v += __shfl_xor(v, m);
                if (tid == 0) KMs[p][i] = v;
            }
        }
    }

    // tiny MLP (relu before each linear) + sigmoid(l1 - l2)
    __syncthreads();
    if (tid < 10) {
        for (int p = 0; p < 2; p++) {
            float acc = b1[tid];
            #pragma unroll
            for (int i = 0; i < 21; i++) acc = fmaf(fmaxf(KMs[p][i], 0.0f), W1[i*10 + tid], acc);
            x1s[p][tid] = acc;
        }
    }
    __syncthreads();
    if (tid < 5) {
        for (int p = 0; p < 2; p++) {
            float acc = b2[tid];
            #pragma unroll
            for (int i = 0; i < 10; i++) acc = fmaf(fmaxf(x1s[p][i], 0.0f), W2[i*5 + tid], acc);
            x2s[p][tid] = acc;
        }
    }
    __syncthreads();
    if (tid == 0) {
        float lv[2];
        for (int p = 0; p < 2; p++) {
            float acc = b3[0];
            #pragma unroll
            for (int i = 0; i < 5; i++) acc = fmaf(fmaxf(x2s[p][i], 0.0f), W3[i], acc);
            lv[p] = acc;
        }
        out[bb] = 1.0f / (1.0f + expf(lv[1] - lv[0]));   // sigmoid(l1 - l2)
    }
}

extern "C" void kernel_launch(void* const* d_in, const int* in_sizes, int n_in,
                              void* d_out, int out_size, void* d_ws, size_t ws_size,
                              hipStream_t stream)
{
    const int*   q1  = (const int*)  d_in[0];
    const int*   d1  = (const int*)  d_in[1];
    const int*   q2  = (const int*)  d_in[2];
    const int*   d2  = (const int*)  d_in[3];
    const float* emb = (const float*)d_in[4];
    const float* W1  = (const float*)d_in[5];
    const float* b1  = (const float*)d_in[6];
    const float* W2  = (const float*)d_in[7];
    const float* b2  = (const float*)d_in[8];
    const float* W3  = (const float*)d_in[9];
    const float* b3  = (const float*)d_in[10];
    float* out = (float*)d_out;
    (void)in_sizes; (void)n_in; (void)d_ws; (void)ws_size;

    knrm_kernel<<<out_size, 256, 0, stream>>>(q1, d1, q2, d2, emb, W1, b1, W2, b2, W3, b3, out);
}

// Round 2
// 175.685 us; speedup vs baseline: 1.4448x; 1.4448x over previous
//
#include <hip/hip_runtime.h>

// KNRM forward, MI355X (gfx950). R1.
// - Matching matrix via 3-term bf16-split MFMA (unchanged from R0, verified absmax 3.9e-3).
// - 20 Gaussian kernels via exact geometric recurrence from mid anchor (mu=0.05):
//     k_{10+j} = t0 * R^j  * e^{-j(j+1)/2},  k_{10-j} = t0 * R^-j * e^{-j(j-1)/2}
//   with t0 = exp(-50(m-0.05)^2), R = e^{10m}. 1 mul + 1 fma per kernel; 4 exp2/element
//   total (anchor, R, 1/R, exact-match) instead of 21.
// - LDS diet: B (q) fragments hoisted to registers once per pass; q-staging and d-chunks
//   share one 32KB buffer -> ~37.6KB/block -> 4 blocks/CU (was 2).

typedef __attribute__((ext_vector_type(8))) short bf16x8;
typedef __attribute__((ext_vector_type(4))) float f32x4;

__device__ __forceinline__ unsigned short f2bf(float f) {   // RNE float->bf16
    unsigned u = __float_as_uint(f);
    u += 0x7fffu + ((u >> 16) & 1u);
    return (unsigned short)(u >> 16);
}
__device__ __forceinline__ float bf2f(unsigned short h) {
    return __uint_as_float(((unsigned)h) << 16);
}

// Gather 64 embedding rows, L2-normalize, split to bf16 hi/lo, store swizzled.
// Element k of row r lives in 16B-chunk ((k>>3) ^ (r&15)) at sub-offset (k&7):
// conflict-free for both staging writes and b128 fragment reads (verified R0: 0 conflicts).
__device__ __forceinline__ void stage_rows(const float* __restrict__ emb,
                                           const int* __restrict__ ids,
                                           unsigned short* __restrict__ hi,
                                           unsigned short* __restrict__ lo,
                                           int tid)
{
    const int lg = tid >> 5;   // row group 0..7
    const int ln = tid & 31;   // lane within row (32 lanes x float4 = 512B row)
    #pragma unroll
    for (int r0 = 0; r0 < 64; r0 += 8) {
        const int row = r0 + lg;
        const int id  = ids[row];
        const float4 v = *reinterpret_cast<const float4*>(emb + (size_t)id * 128 + ln * 4);
        float ss = v.x*v.x + v.y*v.y + v.z*v.z + v.w*v.w;
        #pragma unroll
        for (int m = 16; m >= 1; m >>= 1) ss += __shfl_xor(ss, m);   // 32-lane row reduce
        const float rn = 1.0f / (sqrtf(ss) + 1e-13f);                // reference eps
        const float f0 = v.x*rn, f1 = v.y*rn, f2 = v.z*rn, f3 = v.w*rn;
        const unsigned short h0 = f2bf(f0), h1 = f2bf(f1), h2 = f2bf(f2), h3 = f2bf(f3);
        const unsigned short g0 = f2bf(f0 - bf2f(h0)), g1 = f2bf(f1 - bf2f(h1));
        const unsigned short g2 = f2bf(f2 - bf2f(h2)), g3 = f2bf(f3 - bf2f(h3));
        const int off = row*128 + (((ln >> 1) ^ (row & 15)) << 3) + ((ln & 1) << 2);
        *reinterpret_cast<uint2*>(hi + off) =
            make_uint2((unsigned)h0 | ((unsigned)h1 << 16), (unsigned)h2 | ((unsigned)h3 << 16));
        *reinterpret_cast<uint2*>(lo + off) =
            make_uint2((unsigned)g0 | ((unsigned)g1 << 16), (unsigned)g2 | ((unsigned)g3 << 16));
    }
}

// 21 kernel contributions of one matching value m. sp[i] accumulates the TRUE k_i
// (no post-scale). Cumulative ladder constants are e^{-j(j+1)/2} (up) / e^{-j(j-1)/2} (down).
__device__ __forceinline__ void apply_el(float m, float (&sp)[21]) {
    const float dm = m - 0.05f;
    const float t0 = __builtin_amdgcn_exp2f(dm * dm * -72.13475204444817f);  // k_10
    const float R  = __builtin_amdgcn_exp2f(m *  14.426950408889634f);       // e^{10m}
    const float Ri = __builtin_amdgcn_exp2f(m * -14.426950408889634f);       // e^{-10m}
    sp[10] += t0;
    float tu = t0;
    tu *= R;  sp[11] = fmaf(tu, 3.6787944117e-1f,  sp[11]);  // e^-1
    tu *= R;  sp[12] = fmaf(tu, 4.9787068368e-2f,  sp[12]);  // e^-3
    tu *= R;  sp[13] = fmaf(tu, 2.4787521767e-3f,  sp[13]);  // e^-6
    tu *= R;  sp[14] = fmaf(tu, 4.5399929762e-5f,  sp[14]);  // e^-10
    tu *= R;  sp[15] = fmaf(tu, 3.0590232050e-7f,  sp[15]);  // e^-15
    tu *= R;  sp[16] = fmaf(tu, 7.5825604279e-10f, sp[16]);  // e^-21
    tu *= R;  sp[17] = fmaf(tu, 6.9144001069e-13f, sp[17]);  // e^-28
    tu *= R;  sp[18] = fmaf(tu, 2.3195228302e-16f, sp[18]);  // e^-36
    tu *= R;  sp[19] = fmaf(tu, 2.8625185805e-20f, sp[19]);  // e^-45
    float td = t0;
    td *= Ri; sp[9] += td;                                   // e^0
    td *= Ri; sp[8] = fmaf(td, 3.6787944117e-1f,  sp[8]);    // e^-1
    td *= Ri; sp[7] = fmaf(td, 4.9787068368e-2f,  sp[7]);    // e^-3
    td *= Ri; sp[6] = fmaf(td, 2.4787521767e-3f,  sp[6]);    // e^-6
    td *= Ri; sp[5] = fmaf(td, 4.5399929762e-5f,  sp[5]);    // e^-10
    td *= Ri; sp[4] = fmaf(td, 3.0590232050e-7f,  sp[4]);    // e^-15
    td *= Ri; sp[3] = fmaf(td, 7.5825604279e-10f, sp[3]);    // e^-21
    td *= Ri; sp[2] = fmaf(td, 6.9144001069e-13f, sp[2]);    // e^-28
    td *= Ri; sp[1] = fmaf(td, 2.3195228302e-16f, sp[1]);    // e^-36
    td *= Ri; sp[0] = fmaf(td, 2.8625185805e-20f, sp[0]);    // e^-45
    const float e = m - 1.0f;                                // exact-match (sigma=1e-3)
    sp[20] += __builtin_amdgcn_exp2f(e * e * -721347.5204444817f);
}

__global__ __launch_bounds__(256, 4)
void knrm_kernel(const int* __restrict__ q1, const int* __restrict__ d1,
                 const int* __restrict__ q2, const int* __restrict__ d2,
                 const float* __restrict__ emb,
                 const float* __restrict__ W1, const float* __restrict__ b1,
                 const float* __restrict__ W2, const float* __restrict__ b2,
                 const float* __restrict__ W3, const float* __restrict__ b3,
                 float* __restrict__ out)
{
    __shared__ unsigned short sh_h[64*128], sh_l[64*128];   // 16KB each; q then d chunks
    __shared__ float S[64][21];
    __shared__ float KMs[2][21];
    __shared__ float x1s[2][10], x2s[2][5];

    const int tid = threadIdx.x;
    const int bb  = blockIdx.x;
    const int w   = tid >> 6;     // wave 0..3 -> q rows 16w..16w+15
    const int l   = tid & 63;
    const int lr  = l & 15;       // MFMA row-in-tile (A) / col=q (B,C)
    const int lh  = l >> 4;       // k-group

    for (int p = 0; p < 2; p++) {
        const int* qids = (p == 0 ? q1 : q2) + bb * 64;
        const int* dids = (p == 0 ? d1 : d2) + bb * 256;

        stage_rows(emb, qids, sh_h, sh_l, tid);
        __syncthreads();                                     // q staged

        // Hoist B (q-side) fragments to registers for the whole pass.
        bf16x8 Bh[4], Bl[4];
        const int qrow = w * 16 + lr;
        #pragma unroll
        for (int ks = 0; ks < 4; ks++) {
            const int off = qrow*128 + (((ks*4 + lh) ^ (qrow & 15)) << 3);
            Bh[ks] = *reinterpret_cast<const bf16x8*>(sh_h + off);
            Bl[ks] = *reinterpret_cast<const bf16x8*>(sh_l + off);
        }

        float sp[21];
        #pragma unroll
        for (int i = 0; i < 21; i++) sp[i] = 0.0f;

        for (int c = 0; c < 4; c++) {
            __syncthreads();                                 // prior readers of sh done
            stage_rows(emb, dids + c * 64, sh_h, sh_l, tid);
            __syncthreads();                                 // d chunk staged

            #pragma unroll
            for (int dt = 0; dt < 4; dt += 2) {              // 2 interleaved MFMA chains
                f32x4 C0 = {0.f,0.f,0.f,0.f}, C1 = {0.f,0.f,0.f,0.f};
                #pragma unroll
                for (int ks = 0; ks < 4; ks++) {
                    const int r0 = dt*16 + lr;
                    const int r1 = (dt+1)*16 + lr;
                    const int o0 = r0*128 + (((ks*4 + lh) ^ (r0 & 15)) << 3);
                    const int o1 = r1*128 + (((ks*4 + lh) ^ (r1 & 15)) << 3);
                    const bf16x8 A0h = *reinterpret_cast<const bf16x8*>(sh_h + o0);
                    const bf16x8 A0l = *reinterpret_cast<const bf16x8*>(sh_l + o0);
                    const bf16x8 A1h = *reinterpret_cast<const bf16x8*>(sh_h + o1);
                    const bf16x8 A1l = *reinterpret_cast<const bf16x8*>(sh_l + o1);
                    C0 = __builtin_amdgcn_mfma_f32_16x16x32_bf16(A0h, Bh[ks], C0, 0, 0, 0);
                    C1 = __builtin_amdgcn_mfma_f32_16x16x32_bf16(A1h, Bh[ks], C1, 0, 0, 0);
                    C0 = __builtin_amdgcn_mfma_f32_16x16x32_bf16(A0h, Bl[ks], C0, 0, 0, 0);
                    C1 = __builtin_amdgcn_mfma_f32_16x16x32_bf16(A1h, Bl[ks], C1, 0, 0, 0);
                    C0 = __builtin_amdgcn_mfma_f32_16x16x32_bf16(A0l, Bh[ks], C0, 0, 0, 0);
                    C1 = __builtin_amdgcn_mfma_f32_16x16x32_bf16(A1l, Bh[ks], C1, 0, 0, 0);
                }
                #pragma unroll
                for (int r = 0; r < 4; r++) { apply_el(C0[r], sp); apply_el(C1[r], sp); }
            }
        }

        // Reduce sp over the 4 lanes sharing a q column; sp holds true k sums already.
        #pragma unroll
        for (int i = 0; i < 21; i++) {
            float v = sp[i];
            v += __shfl_xor(v, 16);
            v += __shfl_xor(v, 32);
            sp[i] = v;
        }
        if (l < 16) {
            #pragma unroll
            for (int i = 0; i < 21; i++) S[w*16 + l][i] = sp[i];
        }
        __syncthreads();   // S visible; also orders all chunk-3 LDS reads before next-pass staging

        if (tid < 64) {    // wave 0: KM_i = sum_q log1p(S[q][i])
            #pragma unroll
            for (int i = 0; i < 21; i++) {
                float v = log1pf(S[tid][i]);
                #pragma unroll
                for (int m = 1; m <= 32; m <<= 1) v += __shfl_xor(v, m);
                if (tid == 0) KMs[p][i] = v;
            }
        }
    }

    // tiny MLP (relu before each linear) + sigmoid(l1 - l2)
    __syncthreads();
    if (tid < 10) {
        for (int p = 0; p < 2; p++) {
            float acc = b1[tid];
            #pragma unroll
            for (int i = 0; i < 21; i++) acc = fmaf(fmaxf(KMs[p][i], 0.0f), W1[i*10 + tid], acc);
            x1s[p][tid] = acc;
        }
    }
    __syncthreads();
    if (tid < 5) {
        for (int p = 0; p < 2; p++) {
            float acc = b2[tid];
            #pragma unroll
            for (int i = 0; i < 10; i++) acc = fmaf(fmaxf(x1s[p][i], 0.0f), W2[i*5 + tid], acc);
            x2s[p][tid] = acc;
        }
    }
    __syncthreads();
    if (tid == 0) {
        float lv[2];
        for (int p = 0; p < 2; p++) {
            float acc = b3[0];
            #pragma unroll
            for (int i = 0; i < 5; i++) acc = fmaf(fmaxf(x2s[p][i], 0.0f), W3[i], acc);
            lv[p] = acc;
        }
        out[bb] = 1.0f / (1.0f + expf(lv[1] - lv[0]));   // sigmoid(l1 - l2)
    }
}

extern "C" void kernel_launch(void* const* d_in, const int* in_sizes, int n_in,
                              void* d_out, int out_size, void* d_ws, size_t ws_size,
                              hipStream_t stream)
{
    const int*   q1  = (const int*)  d_in[0];
    const int*   d1  = (const int*)  d_in[1];
    const int*   q2  = (const int*)  d_in[2];
    const int*   d2  = (const int*)  d_in[3];
    const float* emb = (const float*)d_in[4];
    const float* W1  = (const float*)d_in[5];
    const float* b1  = (const float*)d_in[6];
    const float* W2  = (const float*)d_in[7];
    const float* b2  = (const float*)d_in[8];
    const float* W3  = (const float*)d_in[9];
    const float* b3  = (const float*)d_in[10];
    float* out = (float*)d_out;
    (void)in_sizes; (void)n_in; (void)d_ws; (void)ws_size;

    knrm_kernel<<<out_size, 256, 0, stream>>>(q1, d1, q2, d2, emb, W1, b1, W2, b2, W3, b3, out);
}